// Round 15
// baseline (73.665 us; speedup 1.0000x reference)
//
#include <hip/hip_runtime.h>

#define B_ 32
#define C_ 64
#define H_ 96
#define W_ 96
#define P_ 8
#define D_ 256
#define HP 89              // patches per row/col
#define L_ (HP * HP)       // 7921
#define HW (H_ * W_)       // 9216

#define SW 56              // LDS strip row stride in u32 words
#define COPY (P_ * SW)     // 448 words per parity copy
#define NMEANBLK ((B_ * HW / 4) / 64)   // 1152 blocks of 64 threads

// LDS-only barrier (does not drain global stores).
#define LDS_BARRIER() asm volatile("s_waitcnt lgkmcnt(0)\n\ts_barrier" ::: "memory")

typedef __attribute__((ext_vector_type(8))) short bf16x8;
typedef __attribute__((ext_vector_type(4))) float f32x4;

static __device__ inline unsigned f2bf_u(float f) {
    union { float f; unsigned u; } v; v.f = f;
    return (v.u + 0x7FFFu + ((v.u >> 16) & 1u)) >> 16;   // RNE
}

// ---- Kernel 1: channel mean -> packed bf16 (+ W->bf16 in tail blocks) ----
// R7/R12 config (64-thr blocks, unroll 4, NT loads) — measured best.
__global__ __launch_bounds__(64) void mean_kernel(const float* __restrict__ x,
                                                  unsigned short* __restrict__ xmb,
                                                  const float* __restrict__ Wm,
                                                  unsigned short* __restrict__ Wb) {
    if (blockIdx.x >= NMEANBLK) {
        int i = (blockIdx.x - NMEANBLK) * 64 + threadIdx.x;   // 0..4095
        if (i < D_ * P_ * P_ / 4) {
            float4 v = ((const float4*)Wm)[i];
            ushort4 o;
            o.x = (unsigned short)f2bf_u(v.x);
            o.y = (unsigned short)f2bf_u(v.y);
            o.z = (unsigned short)f2bf_u(v.z);
            o.w = (unsigned short)f2bf_u(v.w);
            ((ushort4*)Wb)[i] = o;
        }
        return;
    }
    int idx = blockIdx.x * 64 + threadIdx.x;  // over B*HW/4
    int b   = idx / (HW / 4);
    int hw4 = idx % (HW / 4);
    const f32x4* p = (const f32x4*)(x + (size_t)b * C_ * HW) + hw4;
    f32x4 s = {0.f, 0.f, 0.f, 0.f};
#pragma unroll 4
    for (int c = 0; c < C_; ++c) {
        f32x4 v = __builtin_nontemporal_load(p + (size_t)c * (HW / 4));
        s += v;
    }
    const float inv = 1.0f / C_;
    ushort4 o;
    o.x = (unsigned short)f2bf_u(s.x * inv);
    o.y = (unsigned short)f2bf_u(s.y * inv);
    o.z = (unsigned short)f2bf_u(s.z * inv);
    o.w = (unsigned short)f2bf_u(s.w * inv);
    ((ushort4*)xmb)[idx] = o;
}

// ---- Kernel 2: patch GEMM via MFMA, m-split (3 m-tiles per block, 4
// blocks/CU), W=A orientation -> direct cached f32x4 stores (16 full 64B
// lines per instr), NO LDS-transpose epilogue, NO epilogue barriers. ----
__global__ __launch_bounds__(256, 4) void gemm_kernel(const unsigned short* __restrict__ xmb,
                                                      const unsigned short* __restrict__ Wb,
                                                      const float* __restrict__ bias,
                                                      float* __restrict__ out) {
    __shared__ unsigned strip[2 * COPY];   // 3584 B only
    const int half = blockIdx.x;           // 0: rows 0-47, 1: rows 48-95
    const int hp   = blockIdx.y;
    const int b    = blockIdx.z;
    const int t    = threadIdx.x;
    const int wave = t >> 6;
    const int lane = t & 63;
    const int l15  = lane & 15;
    const int lg   = lane >> 4;
    const int n0   = wave * 64;

    // ---- stage 8 rows of packed bf16, two parity-shifted copies ----
    const unsigned* xu = (const unsigned*)(xmb + (size_t)b * HW) + hp * 48;
    for (int i = t; i < COPY; i += 256) {
        int r = i / SW, w = i - r * SW;
        unsigned u0 = (w < 48) ? xu[r * 48 + w] : 0u;
        unsigned u1 = (w + 1 < 48) ? xu[r * 48 + w + 1] : 0u;
        strip[i]        = u0;
        strip[COPY + i] = (u0 >> 16) | (u1 << 16);
    }

    // ---- W fragments (A-operand): lane holds W[d = n0+nt*16+l15][k = kh*32+lg*8..+7]
    bf16x8 wfrag[2][4];
#pragma unroll
    for (int kh = 0; kh < 2; ++kh)
#pragma unroll
        for (int nt = 0; nt < 4; ++nt) {
            int n = n0 + nt * 16 + l15;
            int k = kh * 32 + lg * 8;
            wfrag[kh][nt] = *(const bf16x8*)(Wb + n * 64 + k);
        }

    // ---- bias init: reg rg <-> d = n0 + nt*16 + lg*4 + rg ----
    f32x4 acc[3][4];
    {
        f32x4 binit[4];
#pragma unroll
        for (int nt = 0; nt < 4; ++nt)
            binit[nt] = *(const f32x4*)(bias + n0 + nt * 16 + lg * 4);
#pragma unroll
        for (int mt = 0; mt < 3; ++mt)
#pragma unroll
            for (int nt = 0; nt < 4; ++nt) acc[mt][nt] = binit[nt];
    }

    LDS_BARRIER();   // strip visible; wfrag loads gated by their own vmcnt

    const unsigned* base = strip + (l15 & 1) * COPY + (l15 >> 1);

#pragma unroll
    for (int kh = 0; kh < 2; ++kh) {
        const int r = kh * 4 + lg;
        bf16x8 pfrag[3];   // B: col m = (half*3+mt)*16 + l15, k = kh*32+lg*8+j
#pragma unroll
        for (int mt = 0; mt < 3; ++mt) {
            union { uint4 u; bf16x8 s; } a;
            const unsigned* p = base + r * SW + (half * 3 + mt) * 8;
            a.u.x = p[0]; a.u.y = p[1]; a.u.z = p[2]; a.u.w = p[3];
            pfrag[mt] = a.s;
        }
#pragma unroll
        for (int nt = 0; nt < 4; ++nt)
#pragma unroll
            for (int mt = 0; mt < 3; ++mt)
                acc[mt][nt] = __builtin_amdgcn_mfma_f32_16x16x32_bf16(
                    wfrag[kh][nt], pfrag[mt], acc[mt][nt], 0, 0, 0);
    }

    // ---- direct cached stores: wp = (half*3+mt)*16 + l15 (row),
    // d = n0 + nt*16 + lg*4 + rg -> one f32x4 per (mt,nt); lanes of one
    // instruction cover 16 complete 64B lines. No epilogue barriers. ----
    float* outp = out + ((size_t)b * L_ + (size_t)hp * HP) * D_ + n0 + lg * 4;
#pragma unroll
    for (int mt = 0; mt < 3; ++mt) {
        const int wp = (half * 3 + mt) * 16 + l15;
        if (wp < HP) {
            float* rowp = outp + (size_t)wp * D_;
#pragma unroll
            for (int nt = 0; nt < 4; ++nt)
                *(f32x4*)(rowp + nt * 16) = acc[mt][nt];
        }
    }
}

extern "C" void kernel_launch(void* const* d_in, const int* in_sizes, int n_in,
                              void* d_out, int out_size, void* d_ws, size_t ws_size,
                              hipStream_t stream) {
    const float* x    = (const float*)d_in[0];
    const float* Wm   = (const float*)d_in[1];
    const float* bias = (const float*)d_in[2];
    float* out = (float*)d_out;

    unsigned short* xmb = (unsigned short*)d_ws;                          // 576 KB
    unsigned short* Wb  = (unsigned short*)((char*)d_ws + (size_t)B_ * HW * 2); // 32 KB

    mean_kernel<<<NMEANBLK + 64, 64, 0, stream>>>(x, xmb, Wm, Wb);

    dim3 grid(2, HP, B_);
    gemm_kernel<<<grid, 256, 0, stream>>>(xmb, Wb, bias, out);
}

// Round 16
// 61.509 us; speedup vs baseline: 1.1976x; 1.1976x over previous
//
#include <hip/hip_runtime.h>

#define B_ 32
#define C_ 64
#define H_ 96
#define W_ 96
#define P_ 8
#define D_ 256
#define HP 89              // patches per row/col
#define L_ (HP * HP)       // 7921
#define HW (H_ * W_)       // 9216

#define SW 56              // LDS strip row stride in u32 words
#define COPY (P_ * SW)     // 448 words per parity copy
#define NMEANBLK ((B_ * HW / 4) / 64)   // 1152 blocks of 64 threads

// LDS-only barrier (does not drain global stores).
#define LDS_BARRIER() asm volatile("s_waitcnt lgkmcnt(0)\n\ts_barrier" ::: "memory")

typedef __attribute__((ext_vector_type(8))) short bf16x8;
typedef __attribute__((ext_vector_type(4))) float f32x4;

static __device__ inline unsigned f2bf_u(float f) {
    union { float f; unsigned u; } v; v.f = f;
    return (v.u + 0x7FFFu + ((v.u >> 16) & 1u)) >> 16;   // RNE
}

// ---- Kernel 1: channel mean -> packed bf16 (+ W->bf16 in tail blocks) ----
// 64-thr blocks, unroll 4, NT loads — measured best (~5.8 TB/s, read floor).
__global__ __launch_bounds__(64) void mean_kernel(const float* __restrict__ x,
                                                  unsigned short* __restrict__ xmb,
                                                  const float* __restrict__ Wm,
                                                  unsigned short* __restrict__ Wb) {
    if (blockIdx.x >= NMEANBLK) {
        int i = (blockIdx.x - NMEANBLK) * 64 + threadIdx.x;   // 0..4095
        if (i < D_ * P_ * P_ / 4) {
            float4 v = ((const float4*)Wm)[i];
            ushort4 o;
            o.x = (unsigned short)f2bf_u(v.x);
            o.y = (unsigned short)f2bf_u(v.y);
            o.z = (unsigned short)f2bf_u(v.z);
            o.w = (unsigned short)f2bf_u(v.w);
            ((ushort4*)Wb)[i] = o;
        }
        return;
    }
    int idx = blockIdx.x * 64 + threadIdx.x;  // over B*HW/4
    int b   = idx / (HW / 4);
    int hw4 = idx % (HW / 4);
    const f32x4* p = (const f32x4*)(x + (size_t)b * C_ * HW) + hw4;
    f32x4 s = {0.f, 0.f, 0.f, 0.f};
#pragma unroll 4
    for (int c = 0; c < C_; ++c) {
        f32x4 v = __builtin_nontemporal_load(p + (size_t)c * (HW / 4));
        s += v;
    }
    const float inv = 1.0f / C_;
    ushort4 o;
    o.x = (unsigned short)f2bf_u(s.x * inv);
    o.y = (unsigned short)f2bf_u(s.y * inv);
    o.z = (unsigned short)f2bf_u(s.z * inv);
    o.w = (unsigned short)f2bf_u(s.w * inv);
    ((ushort4*)xmb)[idx] = o;
}

// ---- Kernel 2: patch GEMM via MFMA, m-split (3 m-tiles per block, 4
// blocks/CU); LDS-transposed epilogue; CACHED 1KB-burst stores; LDS-only
// barriers. Best measured configuration (R12, 61.8 us). ----
__global__ __launch_bounds__(256, 4) void gemm_kernel(const unsigned short* __restrict__ xmb,
                                                      const unsigned short* __restrict__ Wb,
                                                      const float* __restrict__ bias,
                                                      float* __restrict__ out) {
    __shared__ unsigned strip[2 * COPY];   // 3584 B
    __shared__ float tile[16 * 256];       // 16 KB transpose buffer
    const int half = blockIdx.x;           // 0: rows 0-47, 1: rows 48-95
    const int hp   = blockIdx.y;
    const int b    = blockIdx.z;
    const int t    = threadIdx.x;
    const int wave = t >> 6;
    const int lane = t & 63;
    const int l15  = lane & 15;
    const int lg   = lane >> 4;
    const int n0   = wave * 64;

    // ---- stage 8 rows of packed bf16, two parity-shifted copies ----
    const unsigned* xu = (const unsigned*)(xmb + (size_t)b * HW) + hp * 48;
    for (int i = t; i < COPY; i += 256) {
        int r = i / SW, w = i - r * SW;
        unsigned u0 = (w < 48) ? xu[r * 48 + w] : 0u;
        unsigned u1 = (w + 1 < 48) ? xu[r * 48 + w + 1] : 0u;
        strip[i]        = u0;
        strip[COPY + i] = (u0 >> 16) | (u1 << 16);
    }

    // ---- W fragments (A-operand): lane holds W[d = n0+nt*16+l15][k = kh*32+lg*8..+7]
    bf16x8 wfrag[2][4];
#pragma unroll
    for (int kh = 0; kh < 2; ++kh)
#pragma unroll
        for (int nt = 0; nt < 4; ++nt) {
            int n = n0 + nt * 16 + l15;
            int k = kh * 32 + lg * 8;
            wfrag[kh][nt] = *(const bf16x8*)(Wb + n * 64 + k);
        }

    // ---- bias init: reg rg <-> d = n0 + nt*16 + lg*4 + rg ----
    f32x4 acc[3][4];
    {
        f32x4 binit[4];
#pragma unroll
        for (int nt = 0; nt < 4; ++nt)
            binit[nt] = *(const f32x4*)(bias + n0 + nt * 16 + lg * 4);
#pragma unroll
        for (int mt = 0; mt < 3; ++mt)
#pragma unroll
            for (int nt = 0; nt < 4; ++nt) acc[mt][nt] = binit[nt];
    }

    LDS_BARRIER();   // strip visible; wfrag loads gated by their own vmcnt

    const unsigned* base = strip + (l15 & 1) * COPY + (l15 >> 1);

#pragma unroll
    for (int kh = 0; kh < 2; ++kh) {
        const int r = kh * 4 + lg;
        bf16x8 pfrag[3];   // B: col m = (half*3+mt)*16 + l15, k = kh*32+lg*8+j
#pragma unroll
        for (int mt = 0; mt < 3; ++mt) {
            union { uint4 u; bf16x8 s; } a;
            const unsigned* p = base + r * SW + (half * 3 + mt) * 8;
            a.u.x = p[0]; a.u.y = p[1]; a.u.z = p[2]; a.u.w = p[3];
            pfrag[mt] = a.s;
        }
#pragma unroll
        for (int nt = 0; nt < 4; ++nt)
#pragma unroll
            for (int mt = 0; mt < 3; ++mt)
                acc[mt][nt] = __builtin_amdgcn_mfma_f32_16x16x32_bf16(
                    wfrag[kh][nt], pfrag[mt], acc[mt][nt], 0, 0, 0);
    }

    // ---- epilogue: per m-tile, acc -> LDS (XOR-swizzled) -> contiguous rows;
    // LDS-only barriers; cached stores (L2 write-combining path). ----
    float* outbase = out + ((size_t)b * L_ + (size_t)hp * HP) * D_;
#pragma unroll
    for (int mt = 0; mt < 3; ++mt) {
        const int mtg = half * 3 + mt;
        LDS_BARRIER();                         // prior tile reads done
#pragma unroll
        for (int nt = 0; nt < 4; ++nt) {
            int colw = n0 + nt * 16 + lg * 4;
            int w = colw ^ ((l15 & 7) << 2);
            *(f32x4*)&tile[l15 * 256 + w] = acc[mt][nt];
        }
        LDS_BARRIER();                         // tile writes visible
#pragma unroll
        for (int j = 0; j < 4; ++j) {
            int r  = j * 4 + wave;             // tile row, uniform per wave
            int gr = mtg * 16 + r;             // output patch row wp
            if (gr < HP) {
                int w = (lane * 4) ^ ((r & 7) << 2);
                f32x4 v = *(const f32x4*)&tile[r * 256 + w];
                *(f32x4*)(outbase + (size_t)gr * D_ + lane * 4) = v;   // cached
            }
        }
    }
}

extern "C" void kernel_launch(void* const* d_in, const int* in_sizes, int n_in,
                              void* d_out, int out_size, void* d_ws, size_t ws_size,
                              hipStream_t stream) {
    const float* x    = (const float*)d_in[0];
    const float* Wm   = (const float*)d_in[1];
    const float* bias = (const float*)d_in[2];
    float* out = (float*)d_out;

    unsigned short* xmb = (unsigned short*)d_ws;                          // 576 KB
    unsigned short* Wb  = (unsigned short*)((char*)d_ws + (size_t)B_ * HW * 2); // 32 KB

    mean_kernel<<<NMEANBLK + 64, 64, 0, stream>>>(x, xmb, Wm, Wb);

    dim3 grid(2, HP, B_);
    gemm_kernel<<<grid, 256, 0, stream>>>(xmb, Wb, bias, out);
}